// Round 1
// baseline (557.727 us; speedup 1.0000x reference)
//
#include <hip/hip_runtime.h>
#include <math.h>

#define NV   128
#define NROT 16
#define NW   5
#define NR   5
#define NC   6      // 5 feature channels + 1 (denominator)
#define NG   80
#define NOUT 80

constexpr float EPSV = 1e-5f;
constexpr float TWO_PI_F = 6.28318530717958647692f;

__global__ __launch_bounds__(256, 2)
void lsres_kernel(const float* __restrict__ feat,
                  const float* __restrict__ rho,
                  const float* __restrict__ theta,
                  const float* __restrict__ mask,
                  const float* __restrict__ mu_rho,
                  const float* __restrict__ mu_theta,
                  const float* __restrict__ sigma_rho,
                  const float* __restrict__ sigma_theta,
                  const float* __restrict__ Wc,
                  const float* __restrict__ bc,
                  float* __restrict__ out)
{
    // fa[v][cr] with cr = r*6+c, swizzled within-row by ((v>>3)&3)<<3
    __shared__ __align__(16) float fa_lds[NV][32];
    // tg[v][t], swizzled within-row by ((v>>3)&1)<<2
    __shared__ __align__(16) float tg_lds[NV][16];
    __shared__ __align__(16) float C_part[4][32][16];   // per-wave partial C[cr][t]
    __shared__ __align__(16) float C_sum[32][16];
    __shared__ __align__(16) float desc_all[400][20];   // [w*80+g][k], rows padded to 20
    __shared__ float theta_lds[NV];

    const int tid  = threadIdx.x;
    const int site = blockIdx.x;

    // ---------------- Phase A: per-vertex rho gaussians * mask * features ----
    if (tid < NV) {
        const int v = tid;
        const float rv = rho[site*NV + v];
        const float tv = theta[site*NV + v];
        const float mv = mask[site*NV + v];
        theta_lds[v] = tv;
        float f[NC];
        #pragma unroll
        for (int c = 0; c < NW; ++c) f[c] = feat[(site*NV + v)*NW + c];
        f[5] = 1.0f;
        float vals[32];
        #pragma unroll
        for (int r = 0; r < NR; ++r) {
            const float mr  = mu_rho[r*16];          // tiled: same for all w,t
            const float sr  = sigma_rho[r*16];
            const float inv = 1.0f / (sr*sr + EPSV);
            const float d   = rv - mr;
            const float rg  = __expf(-d*d*inv) * mv;
            #pragma unroll
            for (int c = 0; c < NC; ++c) vals[r*6 + c] = rg * f[c];
        }
        vals[30] = 0.0f; vals[31] = 0.0f;            // pad channels -> zero C rows
        const int sw = ((v >> 3) & 3) << 3;
        #pragma unroll
        for (int p = 0; p < 32; ++p) fa_lds[v][p ^ sw] = vals[p];
    }
    __syncthreads();

    // ---------------- per-thread roles ----------------
    const int lane = tid & 63;
    const int wq   = tid >> 6;          // wave id: v-quarter
    const int vs   = lane & 3;          // v-subgroup within wave
    const int tq   = (lane >> 2) & 3;   // theta quad
    const int crq  = lane >> 4;         // channel-8-group

    const int vtg  = tid & 127;         // tg-writer vertex
    const int ht   = tid >> 7;          // tg-writer half (t 0-7 / 8-15)
    const int swt  = ((vtg >> 3) & 1) << 2;
    const float th0 = theta_lds[vtg];

    float mu_t[8], it_[8];
    #pragma unroll
    for (int j = 0; j < 8; ++j) {
        const int t = ht*8 + j;
        mu_t[j] = mu_theta[t];                       // tiled: same for all w,r
        const float st = sigma_theta[t];
        it_[j] = 1.0f / (st*st + EPSV);
    }

    // ---------------- rotation loop ----------------
    for (int k = 0; k < NROT; ++k) {
        // --- theta gaussians for this rotation (lax.rem semantics of jnp.mod) ---
        {
            const float kd = (float)((double)k * 0.39269908169872414); // k*2pi/16 in f64 -> f32
            float x = th0 + kd;
            if (x >= TWO_PI_F) x -= TWO_PI_F;        // exact (Sterbenz) for x in [2pi,4pi)
            float e[8];
            #pragma unroll
            for (int j = 0; j < 8; ++j) {
                const float d = x - mu_t[j];
                e[j] = __expf(-d*d*it_[j]);
            }
            float4 lo = make_float4(e[0], e[1], e[2], e[3]);
            float4 hi = make_float4(e[4], e[5], e[6], e[7]);
            if (swt) { float4 t4 = lo; lo = hi; hi = t4; }
            *(float4*)&tg_lds[vtg][ht*8]     = lo;
            *(float4*)&tg_lds[vtg][ht*8 + 4] = hi;
        }
        __syncthreads();

        // --- B2: C[cr][t] = sum_v fa[v][cr] * tg[v][t] ---
        float acc[8][4];
        #pragma unroll
        for (int j = 0; j < 8; ++j)
            #pragma unroll
            for (int l = 0; l < 4; ++l) acc[j][l] = 0.0f;

        const int fbase = (crq ^ vs) << 3;           // swizzled read base
        const int tbase = (tq ^ (vs & 1)) << 2;
        const int v0 = wq*32 + vs*8;
        #pragma unroll
        for (int i = 0; i < 8; ++i) {
            const int v = v0 + i;
            const float4 fa0 = *(const float4*)&fa_lds[v][fbase];
            const float4 fa1 = *(const float4*)&fa_lds[v][fbase + 4];
            const float4 tg0 = *(const float4*)&tg_lds[v][tbase];
            const float fr[8] = {fa0.x, fa0.y, fa0.z, fa0.w, fa1.x, fa1.y, fa1.z, fa1.w};
            const float tr[4] = {tg0.x, tg0.y, tg0.z, tg0.w};
            #pragma unroll
            for (int j = 0; j < 8; ++j)
                #pragma unroll
                for (int l = 0; l < 4; ++l)
                    acc[j][l] += fr[j] * tr[l];
        }
        // reduce over vs (lanes ^1, ^2)
        #pragma unroll
        for (int j = 0; j < 8; ++j)
            #pragma unroll
            for (int l = 0; l < 4; ++l) {
                float xx = acc[j][l];
                xx += __shfl_xor(xx, 1, 64);
                xx += __shfl_xor(xx, 2, 64);
                acc[j][l] = xx;
            }
        if (vs == 0) {
            #pragma unroll
            for (int j = 0; j < 8; ++j)
                *(float4*)&C_part[wq][crq*8 + j][tq*4] =
                    make_float4(acc[j][0], acc[j][1], acc[j][2], acc[j][3]);
        }
        __syncthreads();

        // --- reduce wave partials ---
        {
            const float* Cp = &C_part[0][0][0];
            float* Cs = &C_sum[0][0];
            #pragma unroll
            for (int q = 0; q < 2; ++q) {
                const int idx = tid + q*256;
                Cs[idx] = Cp[idx] + Cp[idx + 512] + Cp[idx + 1024] + Cp[idx + 1536];
            }
        }
        __syncthreads();

        // --- normalize -> desc_all[w*80+g][k] ---
        #pragma unroll
        for (int q = 0; q < 2; ++q) {
            const int idx = tid + q*256;
            if (idx < 400) {
                const int w = idx / 80;
                const int g = idx - w*80;
                const int r = g >> 4;
                const int t = g & 15;
                const float numer = C_sum[r*6 + w][t];
                const float den   = C_sum[r*6 + 5][t];
                desc_all[idx][k] = numer / (den + EPSV);
            }
        }
        // (no extra barrier needed: next k's C_sum write is two barriers away)
    }
    __syncthreads();

    // ---------------- B3: cf[k][w][o] = desc_k[w,:] @ W[w,:,o]; max over k ----
    if (tid < 200) {
        const int p = tid << 1;          // (w,o) pair, o even
        const int w = p / 80;
        const int o = p - w*80;
        float cfx[16], cfy[16];
        #pragma unroll
        for (int k = 0; k < 16; ++k) { cfx[k] = 0.0f; cfy[k] = 0.0f; }
        const float* Wp = Wc + (w*NG)*NOUT + o;
        #pragma unroll 4
        for (int g = 0; g < NG; ++g) {
            const float2 wv = *(const float2*)(Wp + g*NOUT);
            const float* dp = &desc_all[w*NG + g][0];
            #pragma unroll
            for (int kq = 0; kq < 4; ++kq) {
                const float4 d4 = *(const float4*)(dp + kq*4);
                cfx[kq*4+0] += d4.x*wv.x;  cfy[kq*4+0] += d4.x*wv.y;
                cfx[kq*4+1] += d4.y*wv.x;  cfy[kq*4+1] += d4.y*wv.y;
                cfx[kq*4+2] += d4.z*wv.x;  cfy[kq*4+2] += d4.z*wv.y;
                cfx[kq*4+3] += d4.w*wv.x;  cfy[kq*4+3] += d4.w*wv.y;
            }
        }
        float bx = cfx[0], by = cfy[0];
        #pragma unroll
        for (int k = 1; k < 16; ++k) { bx = fmaxf(bx, cfx[k]); by = fmaxf(by, cfy[k]); }
        bx += bc[w*NOUT + o];
        by += bc[w*NOUT + o + 1];
        float2 res; res.x = bx; res.y = by;
        *(float2*)&out[(site*NW + w)*NOUT + o] = res;
    }
}

extern "C" void kernel_launch(void* const* d_in, const int* in_sizes, int n_in,
                              void* d_out, int out_size, void* d_ws, size_t ws_size,
                              hipStream_t stream) {
    const float* feat        = (const float*)d_in[0];
    const float* rho         = (const float*)d_in[1];
    const float* theta       = (const float*)d_in[2];
    const float* mask        = (const float*)d_in[3];
    const float* mu_rho      = (const float*)d_in[4];
    const float* mu_theta    = (const float*)d_in[5];
    const float* sigma_rho   = (const float*)d_in[6];
    const float* sigma_theta = (const float*)d_in[7];
    const float* Wc          = (const float*)d_in[8];
    const float* bc          = (const float*)d_in[9];
    float* outp              = (float*)d_out;

    const int sites = in_sizes[1] / NV;   // B*S = 4096
    lsres_kernel<<<sites, 256, 0, stream>>>(feat, rho, theta, mask,
                                            mu_rho, mu_theta, sigma_rho, sigma_theta,
                                            Wc, bc, outp);
}

// Round 3
// 151.035 us; speedup vs baseline: 3.6927x; 3.6927x over previous
//
#include <hip/hip_runtime.h>
#include <hip/hip_bf16.h>

#define NV   128
#define NROT 16
#define NW   5

constexpr float EPSV = 1e-5f;
constexpr float TWO_PI_F = 6.28318530717958647692f;

typedef __attribute__((ext_vector_type(8))) short bfrag8;   // 8 bf16 (4 VGPRs)
typedef __attribute__((ext_vector_type(4))) float facc4;    // 4 f32 accum

__device__ __forceinline__ unsigned short f2bf(float x) {
    return __bfloat16_as_ushort(__float2bfloat16(x));
}

// ---------------------------------------------------------------------------
// Pre-pack W into bf16 B-fragment order:
// wf[fid*512 + lane*8 + j] = bf16(W[w][g][o]),  fid = (w*5+ot)*3 + s,
//   o = ot*16 + (lane&15),  g = s*32 + (lane>>4)*8 + j  (0 if g >= 80)
// ---------------------------------------------------------------------------
__global__ void pack_w(const float* __restrict__ Wc, unsigned short* __restrict__ wf) {
    int t = blockIdx.x * blockDim.x + threadIdx.x;
    if (t >= 75 * 64) return;
    const int fid = t >> 6, l = t & 63;
    const int s  = fid % 3, wo = fid / 3;
    const int ot = wo % 5,  w  = wo / 5;
    const int o  = ot * 16 + (l & 15);
    const int g0 = s * 32 + (l >> 4) * 8;
    bfrag8 fv;
    #pragma unroll
    for (int j = 0; j < 8; ++j) {
        const int g = g0 + j;
        const float val = (g < 80) ? Wc[(w * 80 + g) * 80 + o] : 0.0f;
        fv[j] = (short)f2bf(val);
    }
    *(bfrag8*)&wf[(size_t)fid * 512 + l * 8] = fv;
}

// ---------------------------------------------------------------------------
// Main kernel: 1 site per block, 4 waves.
//   Phase A : fa_t[32cr][128v] bf16 (swizzled), theta -> LDS
//   Rotations: wave wq owns k = wq*4 + {0..3}; per k: tg B-frags in regs
//              (32 exps/lane), 8 MFMA -> C[32][16], wave-local normalize ->
//              desc_all[w][k][g] bf16. NO barriers in this loop.
//   B3      : per (w,otile): 3 MFMA over K=96 (padded), max over k rows.
// ---------------------------------------------------------------------------
__global__ __launch_bounds__(256, 3)
void lsres_kernel(const float* __restrict__ feat,
                  const float* __restrict__ rho,
                  const float* __restrict__ theta,
                  const float* __restrict__ mask,
                  const float* __restrict__ mu_rho,
                  const float* __restrict__ mu_theta,
                  const float* __restrict__ sigma_rho,
                  const float* __restrict__ sigma_theta,
                  const float* __restrict__ Wc,
                  const float* __restrict__ bc,
                  const unsigned short* __restrict__ wf,   // may be null
                  float* __restrict__ out)
{
    __shared__ __align__(16) unsigned short fa_t[32 * 128];   // 8 KB, swizzled
    __shared__ __align__(16) float theta_s[NV];               // 0.5 KB
    __shared__ __align__(16) float cbuf[4][16 * 32];          // 8 KB, per-wave, swizzled
    __shared__ __align__(16) unsigned short desc_all[80 * 104]; // 16.25 KB [w*16+k][104]

    const int tid  = threadIdx.x;
    const int lane = tid & 63;
    const int wq   = tid >> 6;
    const int site = blockIdx.x;

    // ---------------- Phase A ----------------
    if (tid < NV) {
        const int v = tid;
        const float rv = rho[site * NV + v];
        const float tv = theta[site * NV + v];
        const float mv = mask[site * NV + v];
        theta_s[v] = tv;
        float f[6];
        #pragma unroll
        for (int c = 0; c < 5; ++c) f[c] = feat[(site * NV + v) * 5 + c];
        f[5] = 1.0f;
        float vals[32];
        #pragma unroll
        for (int r = 0; r < 5; ++r) {
            const float mr  = mu_rho[r * 16];
            const float sr  = sigma_rho[r * 16];
            const float inv = 1.0f / (sr * sr + EPSV);
            const float d   = rv - mr;
            const float rg  = __expf(-d * d * inv) * mv;
            #pragma unroll
            for (int c = 0; c < 6; ++c) vals[r * 6 + c] = rg * f[c];
        }
        vals[30] = 0.0f; vals[31] = 0.0f;
        #pragma unroll
        for (int cr = 0; cr < 32; ++cr) {
            const int byte = cr * 256 + ((v * 2) ^ ((cr & 7) << 4));
            fa_t[byte >> 1] = f2bf(vals[cr]);
        }
    }
    __syncthreads();

    // ---------------- per-wave setup ----------------
    // A-fragments (rotation-invariant): afrag[m][s], lane holds
    // A[cr = m*16+(lane&15)][v = s*32 + (lane>>4)*8 + j]
    bfrag8 afrag[2][4];
    #pragma unroll
    for (int m = 0; m < 2; ++m)
        #pragma unroll
        for (int s = 0; s < 4; ++s) {
            const int cr = m * 16 + (lane & 15);
            const int v0 = s * 32 + (lane >> 4) * 8;
            const int byte = cr * 256 + ((v0 * 2) ^ ((cr & 7) << 4));
            afrag[m][s] = *(const bfrag8*)((const char*)fa_t + byte);
        }

    // theta values this lane needs (B-frag rows): v = s*32 + (lane>>4)*8 + j
    float th[32];
    {
        const int vb = (lane >> 4) * 8;
        #pragma unroll
        for (int s = 0; s < 4; ++s)
            #pragma unroll
            for (int j = 0; j < 8; ++j)
                th[s * 8 + j] = theta_s[vb + s * 32 + j];
    }
    const float mu_t = mu_theta[lane & 15];
    const float st   = sigma_theta[lane & 15];
    const float nit  = -1.0f / (st * st + EPSV);

    float* cw = cbuf[wq];

    // ---------------- rotation loop (barrier-free) ----------------
    for (int i = 0; i < 4; ++i) {
        const int k = wq * 4 + i;
        const float ck = (float)((double)k * 6.283185307179586 * 0.0625);

        facc4 acc0 = {0.f, 0.f, 0.f, 0.f};
        facc4 acc1 = {0.f, 0.f, 0.f, 0.f};
        #pragma unroll
        for (int s = 0; s < 4; ++s) {
            bfrag8 b;
            #pragma unroll
            for (int j = 0; j < 8; ++j) {
                float x = th[s * 8 + j] + ck;
                x = (x >= TWO_PI_F) ? (x - TWO_PI_F) : x;
                const float d = x - mu_t;
                b[j] = (short)f2bf(__expf(d * d * nit));
            }
            acc0 = __builtin_amdgcn_mfma_f32_16x16x32_bf16(afrag[0][s], b, acc0, 0, 0, 0);
            acc1 = __builtin_amdgcn_mfma_f32_16x16x32_bf16(afrag[1][s], b, acc1, 0, 0, 0);
        }

        // write C to wave-private cbuf: D lane layout col=lane&15(t), rows (lane>>4)*4+r
        {
            const int t  = lane & 15;
            const int r0 = (lane >> 4) * 4;
            const int sw = (t & 7) << 4;
            *(facc4*)((char*)cw + t * 128 + (((r0)      * 4) ^ sw)) = acc0;
            *(facc4*)((char*)cw + t * 128 + (((16 + r0) * 4) ^ sw)) = acc1;
        }

        // wave-local normalize -> desc_all[w*16+k][g] (bf16), zero-pad g=80..95
        #pragma unroll
        for (int ii = 0; ii < 8; ++ii) {
            const int idx = lane + ii * 64;
            if (idx < 400) {
                const int w  = idx / 80;
                const int g  = idx - w * 80;
                const int r  = g >> 4, t2 = g & 15;
                const char* base = (const char*)cw + t2 * 128;
                const int sw = (t2 & 7) << 4;
                const float num = *(const float*)(base + (((r * 6 + w) * 4) ^ sw));
                const float den = *(const float*)(base + (((r * 6 + 5) * 4) ^ sw));
                desc_all[(w * 16 + k) * 104 + g] = f2bf(num / (den + EPSV));
            } else if (idx < 480) {
                const int z = idx - 400;
                const int w = z >> 4;
                desc_all[(w * 16 + k) * 104 + 80 + (z & 15)] = 0;
            }
        }
    }
    __syncthreads();

    // ---------------- B3: cf[k][o] = desc[w] @ W[w], max over k ----------------
    for (int u = wq; u < 25; u += 4) {
        const int w  = u / 5;
        const int ot = u - w * 5;
        const int o  = ot * 16 + (lane & 15);
        facc4 acc = {0.f, 0.f, 0.f, 0.f};
        #pragma unroll
        for (int s = 0; s < 3; ++s) {
            // A: row = k = lane&15, kdim g = s*32 + (lane>>4)*8 + j
            const bfrag8 a = *(const bfrag8*)
                &desc_all[(w * 16 + (lane & 15)) * 104 + s * 32 + (lane >> 4) * 8];
            bfrag8 bf;
            if (wf) {
                bf = *(const bfrag8*)&wf[((size_t)((w * 5 + ot) * 3 + s)) * 512 + lane * 8];
            } else {
                #pragma unroll
                for (int j = 0; j < 8; ++j) {
                    const int g = s * 32 + (lane >> 4) * 8 + j;
                    const float val = (g < 80) ? Wc[(w * 80 + g) * 80 + o] : 0.0f;
                    bf[j] = (short)f2bf(val);
                }
            }
            acc = __builtin_amdgcn_mfma_f32_16x16x32_bf16(a, bf, acc, 0, 0, 0);
        }
        // max over k = rows: 4 regs + lane-groups (xor 16, 32)
        float mx = fmaxf(fmaxf(acc[0], acc[1]), fmaxf(acc[2], acc[3]));
        mx = fmaxf(mx, __shfl_xor(mx, 16, 64));
        mx = fmaxf(mx, __shfl_xor(mx, 32, 64));
        if (lane < 16) {
            out[(size_t)site * 400 + w * 80 + o] = mx + bc[w * 80 + o];
        }
    }
}

extern "C" void kernel_launch(void* const* d_in, const int* in_sizes, int n_in,
                              void* d_out, int out_size, void* d_ws, size_t ws_size,
                              hipStream_t stream) {
    const float* feat        = (const float*)d_in[0];
    const float* rho         = (const float*)d_in[1];
    const float* theta       = (const float*)d_in[2];
    const float* mask        = (const float*)d_in[3];
    const float* mu_rho      = (const float*)d_in[4];
    const float* mu_theta    = (const float*)d_in[5];
    const float* sigma_rho   = (const float*)d_in[6];
    const float* sigma_theta = (const float*)d_in[7];
    const float* Wc          = (const float*)d_in[8];
    const float* bc          = (const float*)d_in[9];
    float* outp              = (float*)d_out;

    unsigned short* wf = nullptr;
    if (ws_size >= (size_t)75 * 512 * sizeof(unsigned short)) {
        wf = (unsigned short*)d_ws;
        pack_w<<<19, 256, 0, stream>>>(Wc, wf);
    }

    const int sites = in_sizes[1] / NV;   // B*S = 4096
    lsres_kernel<<<sites, 256, 0, stream>>>(feat, rho, theta, mask,
                                            mu_rho, mu_theta, sigma_rho, sigma_theta,
                                            Wc, bc, wf, outp);
}